// Round 1
// baseline (2442.226 us; speedup 1.0000x reference)
//
#include <hip/hip_runtime.h>

// Problem constants (match reference)
#define N_NODES_C 100000
#define N_EDGES_C 200000
#define N_INC_C   1600000
#define F_IN_C    128
#define H1_C      64
#define H2_C      128

// ---------------- workspace layout (bytes) ----------------
// Dinv   [N_NODES]  fp32
// coef   [N_EDGES]  fp32  (= w/Bdeg)
// R1 (51.2MB): e1 [N_EDGES x 64]  then  h2 [N_NODES x 128]
// R2 (starts 25.6MB region, extended to 102.4MB for e2):
//      h1 [N_NODES x 64]  then  g1 [N_NODES x 64]  then  e2 [N_EDGES x 128]
static constexpr size_t OFF_DINV = 0;
static constexpr size_t OFF_COEF = 400128;                 // align(100000*4)
static constexpr size_t OFF_R1   = 1200128;                // align(OFF_COEF + 200000*4)
static constexpr size_t OFF_R2   = OFF_R1 + (size_t)N_EDGES_C * 64 * 4;  // 52,400,128
// total needed = OFF_R2 + 200000*128*4 = 154,800,128 bytes

// ---------------- kernels ----------------

__global__ void k_degrees(const int* __restrict__ nidx, const int* __restrict__ eidx,
                          const float* __restrict__ w,
                          float* __restrict__ D, float* __restrict__ Bdeg) {
    int i = blockIdx.x * blockDim.x + threadIdx.x;
    int stride = gridDim.x * blockDim.x;
    for (; i < N_INC_C; i += stride) {
        int n = nidx[i];
        int e = eidx[i];
        atomicAdd(&D[n], w[e]);
        atomicAdd(&Bdeg[e], 1.0f);
    }
}

__global__ void k_invert(const float* __restrict__ w,
                         float* __restrict__ Dinv /* holds D on entry */,
                         float* __restrict__ coef /* holds Bdeg on entry */) {
    int i = blockIdx.x * blockDim.x + threadIdx.x;
    int stride = gridDim.x * blockDim.x;
    for (; i < N_EDGES_C; i += stride) {
        if (i < N_NODES_C) {
            float d = Dinv[i];
            Dinv[i] = d > 0.0f ? 1.0f / d : 0.0f;
        }
        float b = coef[i];
        coef[i] = b > 0.0f ? w[i] / b : 0.0f;
    }
}

// Y[nrows x M] = X[nrows x K] @ W[K x M];  K*M*4 <= 32KB LDS
template <int K, int M>
__global__ __launch_bounds__(256) void k_gemm(const float* __restrict__ X,
                                              const float* __restrict__ W,
                                              float* __restrict__ Y, int nrows) {
    constexpr int RPB = 256 / M;  // rows per block
    __shared__ float Ws[K * M];
    __shared__ float Xs[RPB][K];
    for (int t = threadIdx.x; t < K * M; t += 256) Ws[t] = W[t];
    int row0 = blockIdx.x * RPB;
    for (int t = threadIdx.x; t < RPB * K; t += 256) {
        int r = t / K, k = t % K;
        int gr = row0 + r;
        Xs[r][k] = (gr < nrows) ? X[(size_t)gr * K + k] : 0.0f;
    }
    __syncthreads();
    int r = threadIdx.x / M;
    int col = threadIdx.x % M;
    int grow = row0 + r;
    if (grow >= nrows) return;
    float acc = 0.0f;
#pragma unroll 16
    for (int k = 0; k < K; ++k) acc += Xs[r][k] * Ws[k * M + col];
    Y[(size_t)grow * M + col] = acc;
}

// node -> edge scatter:  dst[e] += src[n]   (one wave per incidence)
template <int C>
__global__ void k_scatter_ne(const int* __restrict__ nidx, const int* __restrict__ eidx,
                             const float* __restrict__ src, float* __restrict__ dst) {
    int wid = (blockIdx.x * blockDim.x + threadIdx.x) >> 6;
    int lane = threadIdx.x & 63;
    int nw = (gridDim.x * blockDim.x) >> 6;
    for (int i = wid; i < N_INC_C; i += nw) {
        int n = nidx[i];
        int e = eidx[i];
#pragma unroll
        for (int c = lane; c < C; c += 64)
            atomicAdd(&dst[(size_t)e * C + c], src[(size_t)n * C + c]);
    }
}

// edge -> node scatter with per-edge scale:  dst[n] += coef[e] * src[e]
template <int C>
__global__ void k_scatter_en(const int* __restrict__ nidx, const int* __restrict__ eidx,
                             const float* __restrict__ coef,
                             const float* __restrict__ src, float* __restrict__ dst) {
    int wid = (blockIdx.x * blockDim.x + threadIdx.x) >> 6;
    int lane = threadIdx.x & 63;
    int nw = (gridDim.x * blockDim.x) >> 6;
    for (int i = wid; i < N_INC_C; i += nw) {
        int n = nidx[i];
        int e = eidx[i];
        float s = coef[e];
#pragma unroll
        for (int c = lane; c < C; c += 64)
            atomicAdd(&dst[(size_t)n * C + c], s * src[(size_t)e * C + c]);
    }
}

// Y = relu(Y * Dinv[row] + b[col]), Y is [nrows x C], C power of two
template <int C>
__global__ void k_finalize(float* __restrict__ Y, const float* __restrict__ Dinv,
                           const float* __restrict__ b, int nrows) {
    int i = blockIdx.x * blockDim.x + threadIdx.x;
    int stride = gridDim.x * blockDim.x;
    int total = nrows * C;
    constexpr int SH = (C == 64) ? 6 : 7;
    for (; i < total; i += stride) {
        int row = i >> SH;
        int col = i & (C - 1);
        float v = Y[i] * Dinv[row] + b[col];
        Y[i] = v > 0.0f ? v : 0.0f;
    }
}

// ---------------- host ----------------

extern "C" void kernel_launch(void* const* d_in, const int* in_sizes, int n_in,
                              void* d_out, int out_size, void* d_ws, size_t ws_size,
                              hipStream_t stream) {
    const float* x   = (const float*)d_in[0];
    const int*   eix = (const int*)d_in[1];   // [2, N_INC]: row0=node_idx, row1=edge_idx
    const float* w   = (const float*)d_in[2];
    // d_in[3] = batch (unused)
    const float* W1 = (const float*)d_in[4];
    const float* b1 = (const float*)d_in[5];
    const float* W2 = (const float*)d_in[6];
    const float* b2 = (const float*)d_in[7];
    float* out = (float*)d_out;

    const int* nidx = eix;
    const int* eidx = eix + N_INC_C;

    char* ws = (char*)d_ws;
    float* Dinv = (float*)(ws + OFF_DINV);
    float* coef = (float*)(ws + OFF_COEF);
    float* e1   = (float*)(ws + OFF_R1);   // [N_EDGES x 64]
    float* h2   = (float*)(ws + OFF_R1);   // [N_NODES x 128] (reuses e1, same 51.2MB)
    float* h1   = (float*)(ws + OFF_R2);   // [N_NODES x 64]
    float* g1   = (float*)(ws + OFF_R2);   // [N_NODES x 64] (reuses h1 after scatter1)
    float* e2   = (float*)(ws + OFF_R2);   // [N_EDGES x 128] (reuses g1 after gemm2)

    // ---- normalizers ----
    hipMemsetAsync(Dinv, 0, (size_t)N_NODES_C * 4, stream);
    hipMemsetAsync(coef, 0, (size_t)N_EDGES_C * 4, stream);
    k_degrees<<<1024, 256, 0, stream>>>(nidx, eidx, w, Dinv, coef);
    k_invert<<<(N_EDGES_C + 255) / 256, 256, 0, stream>>>(w, Dinv, coef);

    // ---- layer 1 ----
    k_gemm<F_IN_C, H1_C><<<(N_NODES_C + 3) / 4, 256, 0, stream>>>(x, W1, h1, N_NODES_C);
    hipMemsetAsync(e1, 0, (size_t)N_EDGES_C * H1_C * 4, stream);
    k_scatter_ne<H1_C><<<2048, 256, 0, stream>>>(nidx, eidx, h1, e1);
    hipMemsetAsync(g1, 0, (size_t)N_NODES_C * H1_C * 4, stream);   // h1 dead now
    k_scatter_en<H1_C><<<2048, 256, 0, stream>>>(nidx, eidx, coef, e1, g1);
    k_finalize<H1_C><<<4096, 256, 0, stream>>>(g1, Dinv, b1, N_NODES_C);

    // ---- layer 2 ----
    k_gemm<H1_C, H2_C><<<(N_NODES_C + 1) / 2, 256, 0, stream>>>(g1, W2, h2, N_NODES_C); // e1 dead
    hipMemsetAsync(e2, 0, (size_t)N_EDGES_C * H2_C * 4, stream);   // g1 dead now
    k_scatter_ne<H2_C><<<2048, 256, 0, stream>>>(nidx, eidx, h2, e2);
    hipMemsetAsync(out, 0, (size_t)out_size * 4, stream);
    k_scatter_en<H2_C><<<2048, 256, 0, stream>>>(nidx, eidx, coef, e2, out);
    k_finalize<H2_C><<<4096, 256, 0, stream>>>(out, Dinv, b2, N_NODES_C);
}

// Round 6
// 994.460 us; speedup vs baseline: 2.4558x; 2.4558x over previous
//
#include <hip/hip_runtime.h>

// Problem constants
#define N_NODES_C 100000
#define N_EDGES_C 200000
#define N_INC_C   1600000
#define F_IN_C    128
#define H1_C      64
#define H2_C      128

// ---------------- workspace layout (units of 4 bytes) ----------------
static constexpr size_t U_HIST_E = 0;          // 200000 (int)
static constexpr size_t U_HIST_N = 200000;     // 100000 (int)
static constexpr size_t U_CUR_E  = 300000;     // 200000 (int)
static constexpr size_t U_CUR_N  = 500000;     // 100000 (int)   memset [0, 600000)
static constexpr size_t U_RPE    = 600000;     // 200001 (int)
static constexpr size_t U_RPN    = 800064;     // 100001 (int)
static constexpr size_t U_BSUM   = 900096;     // 256    (int)
static constexpr size_t U_COEF   = 900352;     // 200000 (float)
static constexpr size_t U_DINV   = 1100352;    // 100000 (float)
static constexpr size_t U_CSR_EN = 1200384;    // 1600000 (int)  edge -> node ids
static constexpr size_t U_CSR_NE = 2800384;    // 1600000 (int)  node -> edge ids
static constexpr size_t U_R2     = 4400384;    // 6400000 (float) h1 / g1 / t
static constexpr size_t U_R1     = 10800384;   // 12800000 (float) e1 / s2
// total = 23600384 * 4 B = 94.4 MB

// ---------------- CSR build ----------------

__global__ void k_hist(const int* __restrict__ nidx, const int* __restrict__ eidx,
                       int* __restrict__ hist_n, int* __restrict__ hist_e) {
    int i = blockIdx.x * blockDim.x + threadIdx.x;
    int stride = gridDim.x * blockDim.x;
    for (; i < N_INC_C; i += stride) {
        atomicAdd(&hist_e[eidx[i]], 1);
        atomicAdd(&hist_n[nidx[i]], 1);
    }
}

#define SCAN_ITEMS 8
#define SCAN_CHUNK 2048  // 256 threads * 8

__global__ __launch_bounds__(256) void k_scan_block_sums(const int* __restrict__ in,
                                                         int* __restrict__ bsum, int n) {
    __shared__ int lds[4];
    int base = blockIdx.x * SCAN_CHUNK + threadIdx.x * SCAN_ITEMS;
    int s = 0;
#pragma unroll
    for (int j = 0; j < SCAN_ITEMS; ++j) {
        int idx = base + j;
        s += (idx < n) ? in[idx] : 0;
    }
    for (int d = 1; d < 64; d <<= 1) s += __shfl_xor(s, d);
    if ((threadIdx.x & 63) == 0) lds[threadIdx.x >> 6] = s;
    __syncthreads();
    if (threadIdx.x == 0) bsum[blockIdx.x] = lds[0] + lds[1] + lds[2] + lds[3];
}

// single block of 64 threads, exclusive-scans bsum[0..nb), nb <= 128
__global__ void k_scan_bsum(int* bsum, int nb) {
    int t = threadIdx.x;
    int v0 = (2 * t < nb) ? bsum[2 * t] : 0;
    int v1 = (2 * t + 1 < nb) ? bsum[2 * t + 1] : 0;
    int s = v0 + v1;
    int incl = s;
    for (int d = 1; d < 64; d <<= 1) {
        int u = __shfl_up(incl, d);
        if (t >= d) incl += u;
    }
    int excl = incl - s;
    if (2 * t < nb) bsum[2 * t] = excl;
    if (2 * t + 1 < nb) bsum[2 * t + 1] = excl + v0;
}

__global__ __launch_bounds__(256) void k_scan_write(const int* __restrict__ in,
                                                    const int* __restrict__ bsum,
                                                    int* __restrict__ rowptr, int n, int total) {
    __shared__ int wsum[4];
    int tid = threadIdx.x;
    int base = blockIdx.x * SCAN_CHUNK + tid * SCAN_ITEMS;
    int v[SCAN_ITEMS];
    int s = 0;
#pragma unroll
    for (int j = 0; j < SCAN_ITEMS; ++j) {
        int idx = base + j;
        v[j] = (idx < n) ? in[idx] : 0;
        s += v[j];
    }
    int incl = s;
    int lane = tid & 63;
    for (int d = 1; d < 64; d <<= 1) {
        int u = __shfl_up(incl, d);
        if (lane >= d) incl += u;
    }
    if (lane == 63) wsum[tid >> 6] = incl;
    __syncthreads();
    int woff = 0;
    int w = tid >> 6;
    for (int i = 0; i < w; ++i) woff += wsum[i];
    int excl = woff + (incl - s) + bsum[blockIdx.x];
#pragma unroll
    for (int j = 0; j < SCAN_ITEMS; ++j) {
        int idx = base + j;
        if (idx < n) rowptr[idx] = excl;
        excl += v[j];
    }
    if (blockIdx.x == 0 && tid == 0) rowptr[n] = total;
}

__global__ void k_build(const int* __restrict__ nidx, const int* __restrict__ eidx,
                        const int* __restrict__ rpe, const int* __restrict__ rpn,
                        int* __restrict__ cur_e, int* __restrict__ cur_n,
                        int* __restrict__ csr_e_n, int* __restrict__ csr_n_e) {
    int i = blockIdx.x * blockDim.x + threadIdx.x;
    int stride = gridDim.x * blockDim.x;
    for (; i < N_INC_C; i += stride) {
        int n = nidx[i];
        int e = eidx[i];
        int pe = rpe[e] + atomicAdd(&cur_e[e], 1);
        csr_e_n[pe] = n;
        int pn = rpn[n] + atomicAdd(&cur_n[n], 1);
        csr_n_e[pn] = e;
    }
}

__global__ void k_coef(const float* __restrict__ w, const int* __restrict__ rpe,
                       float* __restrict__ coef) {
    int i = blockIdx.x * blockDim.x + threadIdx.x;
    if (i >= N_EDGES_C) return;
    int bd = rpe[i + 1] - rpe[i];
    coef[i] = (bd > 0) ? w[i] / (float)bd : 0.0f;
}

__global__ void k_dinv(const int* __restrict__ rpn, const int* __restrict__ csr_n_e,
                       const float* __restrict__ w, float* __restrict__ Dinv) {
    int i = blockIdx.x * blockDim.x + threadIdx.x;
    if (i >= N_NODES_C) return;
    int s0 = rpn[i], s1 = rpn[i + 1];
    float s = 0.0f;
    for (int k = s0; k < s1; ++k) s += w[csr_n_e[k]];
    Dinv[i] = (s > 0.0f) ? 1.0f / s : 0.0f;
}

// ---------------- dense GEMMs ----------------

// Y[nrows x M] = X[nrows x K] @ W[K x M]
template <int K, int M>
__global__ __launch_bounds__(256) void k_gemm(const float* __restrict__ X,
                                              const float* __restrict__ W,
                                              float* __restrict__ Y, int nrows) {
    constexpr int RPB = 256 / M;
    __shared__ float Ws[K * M];
    __shared__ float Xs[RPB][K];
    for (int t = threadIdx.x; t < K * M; t += 256) Ws[t] = W[t];
    int row0 = blockIdx.x * RPB;
    for (int t = threadIdx.x; t < RPB * K; t += 256) {
        int r = t / K, k = t % K;
        int gr = row0 + r;
        Xs[r][k] = (gr < nrows) ? X[(size_t)gr * K + k] : 0.0f;
    }
    __syncthreads();
    int r = threadIdx.x / M;
    int col = threadIdx.x % M;
    int grow = row0 + r;
    if (grow >= nrows) return;
    float acc = 0.0f;
#pragma unroll 16
    for (int k = 0; k < K; ++k) acc += Xs[r][k] * Ws[k * M + col];
    Y[(size_t)grow * M + col] = acc;
}

// out[nrows x 128] = relu(X[nrows x 64] @ W[64 x 128] + bias)
__global__ __launch_bounds__(256) void k_gemm2_ep(const float* __restrict__ X,
                                                  const float* __restrict__ W,
                                                  const float* __restrict__ bias,
                                                  float* __restrict__ Y, int nrows) {
    __shared__ float Ws[64 * 128];
    __shared__ float Xs[2][64];
    for (int t = threadIdx.x; t < 64 * 128; t += 256) Ws[t] = W[t];
    int row0 = blockIdx.x * 2;
    if (threadIdx.x < 128) {
        int r = threadIdx.x >> 6, k = threadIdx.x & 63;
        int gr = row0 + r;
        Xs[r][k] = (gr < nrows) ? X[(size_t)gr * 64 + k] : 0.0f;
    }
    __syncthreads();
    int r = threadIdx.x >> 7;
    int col = threadIdx.x & 127;
    int grow = row0 + r;
    if (grow >= nrows) return;
    float acc = 0.0f;
#pragma unroll
    for (int k = 0; k < 64; ++k) acc += Xs[r][k] * Ws[k * 128 + col];
    float v = acc + bias[col];
    Y[(size_t)grow * 128 + col] = v > 0.0f ? v : 0.0f;
}

// ---------------- CSR gathers (64 channels, one wave per row) ----------------

// dst[r][c] = sum over cols of src[col][c]
__global__ __launch_bounds__(256) void k_gather_ne64(const int* __restrict__ rowptr,
                                                     const int* __restrict__ cols,
                                                     const float* __restrict__ src,
                                                     float* __restrict__ dst, int nrows) {
    int wid = (blockIdx.x * 256 + threadIdx.x) >> 6;
    int lane = threadIdx.x & 63;
    int nw = (gridDim.x * 256) >> 6;
    for (int r = wid; r < nrows; r += nw) {
        int s0 = rowptr[r];
        int deg = rowptr[r + 1] - s0;
        float acc = 0.0f;
        for (int base = 0; base < deg; base += 64) {
            int m = deg - base;
            if (m > 64) m = 64;
            int myc = (base + lane < deg) ? cols[s0 + base + lane] : 0;
            for (int j = 0; j < m; ++j) {
                int c = __shfl(myc, j);
                acc += src[(size_t)c * 64 + lane];
            }
        }
        dst[(size_t)r * 64 + lane] = acc;
    }
}

// dst[r][c] = f( Dinv[r] * sum over cols e of coef[e]*src[e][c] )
// FIN=1: also + bias, relu.  FIN=0: Dinv scale only.
template <int FIN>
__global__ __launch_bounds__(256) void k_gather_en64(const int* __restrict__ rowptr,
                                                     const int* __restrict__ cols,
                                                     const float* __restrict__ coef,
                                                     const float* __restrict__ src,
                                                     const float* __restrict__ Dinv,
                                                     const float* __restrict__ bias,
                                                     float* __restrict__ dst, int nrows) {
    int wid = (blockIdx.x * 256 + threadIdx.x) >> 6;
    int lane = threadIdx.x & 63;
    int nw = (gridDim.x * 256) >> 6;
    for (int r = wid; r < nrows; r += nw) {
        int s0 = rowptr[r];
        int deg = rowptr[r + 1] - s0;
        float acc = 0.0f;
        for (int base = 0; base < deg; base += 64) {
            int m = deg - base;
            if (m > 64) m = 64;
            bool valid = (base + lane < deg);
            int myc = valid ? cols[s0 + base + lane] : 0;
            float mycf = valid ? coef[myc] : 0.0f;
            for (int j = 0; j < m; ++j) {
                int c = __shfl(myc, j);
                float cf = __shfl(mycf, j);
                acc += cf * src[(size_t)c * 64 + lane];
            }
        }
        float v = acc * Dinv[r];
        if (FIN) {
            v += bias[lane];
            v = v > 0.0f ? v : 0.0f;
        }
        dst[(size_t)r * 64 + lane] = v;
    }
}

// ---------------- host ----------------

extern "C" void kernel_launch(void* const* d_in, const int* in_sizes, int n_in,
                              void* d_out, int out_size, void* d_ws, size_t ws_size,
                              hipStream_t stream) {
    const float* x   = (const float*)d_in[0];
    const int*   eix = (const int*)d_in[1];
    const float* w   = (const float*)d_in[2];
    const float* W1  = (const float*)d_in[4];
    const float* b1  = (const float*)d_in[5];
    const float* W2  = (const float*)d_in[6];
    const float* b2  = (const float*)d_in[7];
    float* out = (float*)d_out;

    const int* nidx = eix;
    const int* eidx = eix + N_INC_C;

    int*   wsI = (int*)d_ws;
    float* wsF = (float*)d_ws;
    int* hist_e = wsI + U_HIST_E;
    int* hist_n = wsI + U_HIST_N;
    int* cur_e  = wsI + U_CUR_E;
    int* cur_n  = wsI + U_CUR_N;
    int* rpe    = wsI + U_RPE;
    int* rpn    = wsI + U_RPN;
    int* bsum   = wsI + U_BSUM;
    float* coef = wsF + U_COEF;
    float* Dinv = wsF + U_DINV;
    int* csr_e_n = wsI + U_CSR_EN;
    int* csr_n_e = wsI + U_CSR_NE;
    float* h1 = wsF + U_R2;   // [N_NODES x 64]
    float* g1 = wsF + U_R2;   // reuses h1 (h1 dead when g1 written)
    float* t2 = wsF + U_R2;   // reuses g1 (g1 dead when t2 written)
    float* e1 = wsF + U_R1;   // [N_EDGES x 64]
    float* s2 = wsF + U_R1;   // reuses e1

    // ---- CSR build ----
    hipMemsetAsync(wsI, 0, 600000 * sizeof(int), stream);  // hist_e/n + cur_e/n
    k_hist<<<2048, 256, 0, stream>>>(nidx, eidx, hist_n, hist_e);

    int nb_e = (N_EDGES_C + SCAN_CHUNK - 1) / SCAN_CHUNK;   // 98
    int nb_n = (N_NODES_C + SCAN_CHUNK - 1) / SCAN_CHUNK;   // 49
    k_scan_block_sums<<<nb_e, 256, 0, stream>>>(hist_e, bsum, N_EDGES_C);
    k_scan_bsum<<<1, 64, 0, stream>>>(bsum, nb_e);
    k_scan_write<<<nb_e, 256, 0, stream>>>(hist_e, bsum, rpe, N_EDGES_C, N_INC_C);
    k_scan_block_sums<<<nb_n, 256, 0, stream>>>(hist_n, bsum, N_NODES_C);
    k_scan_bsum<<<1, 64, 0, stream>>>(bsum, nb_n);
    k_scan_write<<<nb_n, 256, 0, stream>>>(hist_n, bsum, rpn, N_NODES_C, N_INC_C);

    k_build<<<2048, 256, 0, stream>>>(nidx, eidx, rpe, rpn, cur_e, cur_n, csr_e_n, csr_n_e);
    k_coef<<<(N_EDGES_C + 255) / 256, 256, 0, stream>>>(w, rpe, coef);
    k_dinv<<<(N_NODES_C + 255) / 256, 256, 0, stream>>>(rpn, csr_n_e, w, Dinv);

    // ---- layer 1 ----
    k_gemm<F_IN_C, H1_C><<<(N_NODES_C + 3) / 4, 256, 0, stream>>>(x, W1, h1, N_NODES_C);
    k_gather_ne64<<<(N_EDGES_C * 64 + 255) / 256, 256, 0, stream>>>(rpe, csr_e_n, h1, e1, N_EDGES_C);
    k_gather_en64<1><<<(N_NODES_C * 64 + 255) / 256, 256, 0, stream>>>(rpn, csr_n_e, coef, e1,
                                                                       Dinv, b1, g1, N_NODES_C);

    // ---- layer 2 (aggregate in 64-dim, project 64->128 last) ----
    k_gather_ne64<<<(N_EDGES_C * 64 + 255) / 256, 256, 0, stream>>>(rpe, csr_e_n, g1, s2, N_EDGES_C);
    k_gather_en64<0><<<(N_NODES_C * 64 + 255) / 256, 256, 0, stream>>>(rpn, csr_n_e, coef, s2,
                                                                       Dinv, nullptr, t2, N_NODES_C);
    k_gemm2_ep<<<(N_NODES_C + 1) / 2, 256, 0, stream>>>(t2, W2, b2, out, N_NODES_C);
}

// Round 7
// 716.223 us; speedup vs baseline: 3.4099x; 1.3885x over previous
//
#include <hip/hip_runtime.h>

// Problem constants
#define N_NODES_C 100000
#define N_EDGES_C 200000
#define N_INC_C   1600000
#define F_IN_C    128
#define H1_C      64
#define H2_C      128

// ---------------- workspace layout (units of 4 bytes) ----------------
static constexpr size_t U_HIST_E = 0;          // 200000 (int)
static constexpr size_t U_HIST_N = 200000;     // 100000 (int)   memset [0, 300000)
static constexpr size_t U_RPE    = 300000;     // 200001 (int)
static constexpr size_t U_RPN    = 500032;     // 100001 (int)
static constexpr size_t U_BSUM   = 600064;     // 256    (int)
static constexpr size_t U_COEF   = 600320;     // 200000 (float)
static constexpr size_t U_DINV   = 800320;     // 100000 (float)
static constexpr size_t U_RANK_E = 900320;     // 1600000 (int)
static constexpr size_t U_RANK_N = 2500320;    // 1600000 (int)
static constexpr size_t U_CSR_EN = 4100320;    // 1600000 (int)  edge -> node ids
static constexpr size_t U_CSR_NE = 5700320;    // 1600000 (int)  node -> edge ids
static constexpr size_t U_R2     = 7300320;    // 6400000 (float) h1 / g1 / t2
static constexpr size_t U_R1     = 13700320;   // 12800000 (float) e1 / s2
// total = 26500320 * 4 B = 106 MB

// ---------------- CSR build ----------------

// histogram + per-incidence rank (rank writes are coalesced)
__global__ void k_hist_rank(const int* __restrict__ nidx, const int* __restrict__ eidx,
                            int* __restrict__ hist_n, int* __restrict__ hist_e,
                            int* __restrict__ rank_n, int* __restrict__ rank_e) {
    int i = blockIdx.x * blockDim.x + threadIdx.x;
    int stride = gridDim.x * blockDim.x;
    for (; i < N_INC_C; i += stride) {
        rank_e[i] = atomicAdd(&hist_e[eidx[i]], 1);
        rank_n[i] = atomicAdd(&hist_n[nidx[i]], 1);
    }
}

#define SCAN_ITEMS 8
#define SCAN_CHUNK 2048  // 256 threads * 8

__global__ __launch_bounds__(256) void k_scan_block_sums(const int* __restrict__ in,
                                                         int* __restrict__ bsum, int n) {
    __shared__ int lds[4];
    int base = blockIdx.x * SCAN_CHUNK + threadIdx.x * SCAN_ITEMS;
    int s = 0;
#pragma unroll
    for (int j = 0; j < SCAN_ITEMS; ++j) {
        int idx = base + j;
        s += (idx < n) ? in[idx] : 0;
    }
    for (int d = 1; d < 64; d <<= 1) s += __shfl_xor(s, d);
    if ((threadIdx.x & 63) == 0) lds[threadIdx.x >> 6] = s;
    __syncthreads();
    if (threadIdx.x == 0) bsum[blockIdx.x] = lds[0] + lds[1] + lds[2] + lds[3];
}

// single block of 64 threads, exclusive-scans bsum[0..nb), nb <= 128
__global__ void k_scan_bsum(int* bsum, int nb) {
    int t = threadIdx.x;
    int v0 = (2 * t < nb) ? bsum[2 * t] : 0;
    int v1 = (2 * t + 1 < nb) ? bsum[2 * t + 1] : 0;
    int s = v0 + v1;
    int incl = s;
    for (int d = 1; d < 64; d <<= 1) {
        int u = __shfl_up(incl, d);
        if (t >= d) incl += u;
    }
    int excl = incl - s;
    if (2 * t < nb) bsum[2 * t] = excl;
    if (2 * t + 1 < nb) bsum[2 * t + 1] = excl + v0;
}

__global__ __launch_bounds__(256) void k_scan_write(const int* __restrict__ in,
                                                    const int* __restrict__ bsum,
                                                    int* __restrict__ rowptr, int n, int total) {
    __shared__ int wsum[4];
    int tid = threadIdx.x;
    int base = blockIdx.x * SCAN_CHUNK + tid * SCAN_ITEMS;
    int v[SCAN_ITEMS];
    int s = 0;
#pragma unroll
    for (int j = 0; j < SCAN_ITEMS; ++j) {
        int idx = base + j;
        v[j] = (idx < n) ? in[idx] : 0;
        s += v[j];
    }
    int incl = s;
    int lane = tid & 63;
    for (int d = 1; d < 64; d <<= 1) {
        int u = __shfl_up(incl, d);
        if (lane >= d) incl += u;
    }
    if (lane == 63) wsum[tid >> 6] = incl;
    __syncthreads();
    int woff = 0;
    int w = tid >> 6;
    for (int i = 0; i < w; ++i) woff += wsum[i];
    int excl = woff + (incl - s) + bsum[blockIdx.x];
#pragma unroll
    for (int j = 0; j < SCAN_ITEMS; ++j) {
        int idx = base + j;
        if (idx < n) rowptr[idx] = excl;
        excl += v[j];
    }
    if (blockIdx.x == 0 && tid == 0) rowptr[n] = total;
}

// placement: one random-write stream per kernel, no atomics
__global__ void k_place_e(const int* __restrict__ nidx, const int* __restrict__ eidx,
                          const int* __restrict__ rank_e, const int* __restrict__ rpe,
                          int* __restrict__ csr_e_n) {
    int i = blockIdx.x * blockDim.x + threadIdx.x;
    int stride = gridDim.x * blockDim.x;
    for (; i < N_INC_C; i += stride)
        csr_e_n[rpe[eidx[i]] + rank_e[i]] = nidx[i];
}

__global__ void k_place_n(const int* __restrict__ nidx, const int* __restrict__ eidx,
                          const int* __restrict__ rank_n, const int* __restrict__ rpn,
                          int* __restrict__ csr_n_e) {
    int i = blockIdx.x * blockDim.x + threadIdx.x;
    int stride = gridDim.x * blockDim.x;
    for (; i < N_INC_C; i += stride)
        csr_n_e[rpn[nidx[i]] + rank_n[i]] = eidx[i];
}

__global__ void k_coef(const float* __restrict__ w, const int* __restrict__ rpe,
                       float* __restrict__ coef) {
    int i = blockIdx.x * blockDim.x + threadIdx.x;
    if (i >= N_EDGES_C) return;
    int bd = rpe[i + 1] - rpe[i];
    coef[i] = (bd > 0) ? w[i] / (float)bd : 0.0f;
}

__global__ void k_dinv(const int* __restrict__ rpn, const int* __restrict__ csr_n_e,
                       const float* __restrict__ w, float* __restrict__ Dinv) {
    int i = blockIdx.x * blockDim.x + threadIdx.x;
    if (i >= N_NODES_C) return;
    int s0 = rpn[i], s1 = rpn[i + 1];
    float s = 0.0f;
    for (int k = s0; k < s1; ++k) s += w[csr_n_e[k]];
    Dinv[i] = (s > 0.0f) ? 1.0f / s : 0.0f;
}

// ---------------- dense GEMMs ----------------

// Y[nrows x M] = X[nrows x K] @ W[K x M]
template <int K, int M>
__global__ __launch_bounds__(256) void k_gemm(const float* __restrict__ X,
                                              const float* __restrict__ W,
                                              float* __restrict__ Y, int nrows) {
    constexpr int RPB = 256 / M;
    __shared__ float Ws[K * M];
    __shared__ float Xs[RPB][K];
    for (int t = threadIdx.x; t < K * M; t += 256) Ws[t] = W[t];
    int row0 = blockIdx.x * RPB;
    for (int t = threadIdx.x; t < RPB * K; t += 256) {
        int r = t / K, k = t % K;
        int gr = row0 + r;
        Xs[r][k] = (gr < nrows) ? X[(size_t)gr * K + k] : 0.0f;
    }
    __syncthreads();
    int r = threadIdx.x / M;
    int col = threadIdx.x % M;
    int grow = row0 + r;
    if (grow >= nrows) return;
    float acc = 0.0f;
#pragma unroll 16
    for (int k = 0; k < K; ++k) acc += Xs[r][k] * Ws[k * M + col];
    Y[(size_t)grow * M + col] = acc;
}

// out[nrows x 128] = relu(X[nrows x 64] @ W[64 x 128] + bias)
__global__ __launch_bounds__(256) void k_gemm2_ep(const float* __restrict__ X,
                                                  const float* __restrict__ W,
                                                  const float* __restrict__ bias,
                                                  float* __restrict__ Y, int nrows) {
    __shared__ float Ws[64 * 128];
    __shared__ float Xs[2][64];
    for (int t = threadIdx.x; t < 64 * 128; t += 256) Ws[t] = W[t];
    int row0 = blockIdx.x * 2;
    if (threadIdx.x < 128) {
        int r = threadIdx.x >> 6, k = threadIdx.x & 63;
        int gr = row0 + r;
        Xs[r][k] = (gr < nrows) ? X[(size_t)gr * 64 + k] : 0.0f;
    }
    __syncthreads();
    int r = threadIdx.x >> 7;
    int col = threadIdx.x & 127;
    int grow = row0 + r;
    if (grow >= nrows) return;
    float acc = 0.0f;
#pragma unroll
    for (int k = 0; k < 64; ++k) acc += Xs[r][k] * Ws[k * 128 + col];
    float v = acc + bias[col];
    Y[(size_t)grow * 128 + col] = v > 0.0f ? v : 0.0f;
}

// ---------------- CSR gathers: 4 neighbor-groups x 16 lanes x float4 ----------------
// EN=0: dst[r] = sum_{c in row} src[c]            (node -> edge)
// EN=1: dst[r] = Dinv[r] * sum coef[c]*src[c]     (edge -> node), FIN: +bias, relu
template <int EN, int FIN>
__global__ __launch_bounds__(256) void k_gather_v4(const int* __restrict__ rowptr,
                                                   const int* __restrict__ cols,
                                                   const float* __restrict__ coef,
                                                   const float* __restrict__ src,
                                                   const float* __restrict__ Dinv,
                                                   const float* __restrict__ bias,
                                                   float* __restrict__ dst, int nrows) {
    int wid = (blockIdx.x * 256 + threadIdx.x) >> 6;
    int lane = threadIdx.x & 63;
    int g = lane >> 4;        // neighbor group 0..3
    int gl = lane & 15;       // lane within group -> channels [gl*4, gl*4+4)
    int nw = (gridDim.x * 256) >> 6;
    for (int r = wid; r < nrows; r += nw) {
        int s0 = rowptr[r], s1 = rowptr[r + 1];
        float ax = 0.0f, ay = 0.0f, az = 0.0f, aw = 0.0f;
        for (int j = s0 + g; j < s1; j += 4) {
            int c = cols[j];  // uniform within group
            float s = EN ? coef[c] : 1.0f;
            const float4 v = *reinterpret_cast<const float4*>(&src[(size_t)c * 64 + gl * 4]);
            ax += s * v.x; ay += s * v.y; az += s * v.z; aw += s * v.w;
        }
        // reduce the 4 neighbor groups
        ax += __shfl_xor(ax, 16); ay += __shfl_xor(ay, 16);
        az += __shfl_xor(az, 16); aw += __shfl_xor(aw, 16);
        ax += __shfl_xor(ax, 32); ay += __shfl_xor(ay, 32);
        az += __shfl_xor(az, 32); aw += __shfl_xor(aw, 32);
        if (g == 0) {
            float4 o;
            o.x = ax; o.y = ay; o.z = az; o.w = aw;
            if (EN) {
                float dv = Dinv[r];
                o.x *= dv; o.y *= dv; o.z *= dv; o.w *= dv;
            }
            if (FIN) {
                const float4 b4 = *reinterpret_cast<const float4*>(&bias[gl * 4]);
                o.x += b4.x; o.y += b4.y; o.z += b4.z; o.w += b4.w;
                o.x = o.x > 0.0f ? o.x : 0.0f;
                o.y = o.y > 0.0f ? o.y : 0.0f;
                o.z = o.z > 0.0f ? o.z : 0.0f;
                o.w = o.w > 0.0f ? o.w : 0.0f;
            }
            *reinterpret_cast<float4*>(&dst[(size_t)r * 64 + gl * 4]) = o;
        }
    }
}

// ---------------- host ----------------

extern "C" void kernel_launch(void* const* d_in, const int* in_sizes, int n_in,
                              void* d_out, int out_size, void* d_ws, size_t ws_size,
                              hipStream_t stream) {
    const float* x   = (const float*)d_in[0];
    const int*   eix = (const int*)d_in[1];
    const float* w   = (const float*)d_in[2];
    const float* W1  = (const float*)d_in[4];
    const float* b1  = (const float*)d_in[5];
    const float* W2  = (const float*)d_in[6];
    const float* b2  = (const float*)d_in[7];
    float* out = (float*)d_out;

    const int* nidx = eix;
    const int* eidx = eix + N_INC_C;

    int*   wsI = (int*)d_ws;
    float* wsF = (float*)d_ws;
    int* hist_e = wsI + U_HIST_E;
    int* hist_n = wsI + U_HIST_N;
    int* rpe    = wsI + U_RPE;
    int* rpn    = wsI + U_RPN;
    int* bsum   = wsI + U_BSUM;
    float* coef = wsF + U_COEF;
    float* Dinv = wsF + U_DINV;
    int* rank_e = wsI + U_RANK_E;
    int* rank_n = wsI + U_RANK_N;
    int* csr_e_n = wsI + U_CSR_EN;
    int* csr_n_e = wsI + U_CSR_NE;
    float* h1 = wsF + U_R2;   // [N_NODES x 64]
    float* g1 = wsF + U_R2;   // reuses h1 (h1 dead when g1 written)
    float* t2 = wsF + U_R2;   // reuses g1 (g1 dead when t2 written)
    float* e1 = wsF + U_R1;   // [N_EDGES x 64]
    float* s2 = wsF + U_R1;   // reuses e1

    // ---- CSR build ----
    hipMemsetAsync(wsI, 0, 300000 * sizeof(int), stream);  // hist_e + hist_n
    k_hist_rank<<<2048, 256, 0, stream>>>(nidx, eidx, hist_n, hist_e, rank_n, rank_e);

    int nb_e = (N_EDGES_C + SCAN_CHUNK - 1) / SCAN_CHUNK;   // 98
    int nb_n = (N_NODES_C + SCAN_CHUNK - 1) / SCAN_CHUNK;   // 49
    k_scan_block_sums<<<nb_e, 256, 0, stream>>>(hist_e, bsum, N_EDGES_C);
    k_scan_bsum<<<1, 64, 0, stream>>>(bsum, nb_e);
    k_scan_write<<<nb_e, 256, 0, stream>>>(hist_e, bsum, rpe, N_EDGES_C, N_INC_C);
    k_scan_block_sums<<<nb_n, 256, 0, stream>>>(hist_n, bsum, N_NODES_C);
    k_scan_bsum<<<1, 64, 0, stream>>>(bsum, nb_n);
    k_scan_write<<<nb_n, 256, 0, stream>>>(hist_n, bsum, rpn, N_NODES_C, N_INC_C);

    k_place_e<<<2048, 256, 0, stream>>>(nidx, eidx, rank_e, rpe, csr_e_n);
    k_place_n<<<2048, 256, 0, stream>>>(nidx, eidx, rank_n, rpn, csr_n_e);
    k_coef<<<(N_EDGES_C + 255) / 256, 256, 0, stream>>>(w, rpe, coef);
    k_dinv<<<(N_NODES_C + 255) / 256, 256, 0, stream>>>(rpn, csr_n_e, w, Dinv);

    // ---- layer 1 ----
    k_gemm<F_IN_C, H1_C><<<(N_NODES_C + 3) / 4, 256, 0, stream>>>(x, W1, h1, N_NODES_C);
    k_gather_v4<0, 0><<<(N_EDGES_C + 3) / 4, 256, 0, stream>>>(rpe, csr_e_n, nullptr, h1,
                                                               nullptr, nullptr, e1, N_EDGES_C);
    k_gather_v4<1, 1><<<(N_NODES_C + 3) / 4, 256, 0, stream>>>(rpn, csr_n_e, coef, e1,
                                                               Dinv, b1, g1, N_NODES_C);

    // ---- layer 2 (aggregate in 64-dim, project 64->128 last) ----
    k_gather_v4<0, 0><<<(N_EDGES_C + 3) / 4, 256, 0, stream>>>(rpe, csr_e_n, nullptr, g1,
                                                               nullptr, nullptr, s2, N_EDGES_C);
    k_gather_v4<1, 0><<<(N_NODES_C + 3) / 4, 256, 0, stream>>>(rpn, csr_n_e, coef, s2,
                                                               Dinv, nullptr, t2, N_NODES_C);
    k_gemm2_ep<<<(N_NODES_C + 1) / 2, 256, 0, stream>>>(t2, W2, b2, out, N_NODES_C);
}

// Round 8
// 568.545 us; speedup vs baseline: 4.2956x; 1.2597x over previous
//
#include <hip/hip_runtime.h>

// Problem constants
#define N_NODES_C 100000
#define N_EDGES_C 200000
#define N_INC_C   1600000
#define F_IN_C    128
#define H1_C      64
#define H2_C      128

// ---------------- workspace layout (units of 4 bytes) ----------------
static constexpr size_t U_HIST_E = 0;          // 200000 (int)
static constexpr size_t U_HIST_N = 200000;     // 100000 (int)   memset [0, 300000)
static constexpr size_t U_RPE    = 300000;     // 200001 (int)
static constexpr size_t U_RPN    = 500032;     // 100001 (int)
static constexpr size_t U_BSUM   = 600064;     // 256    (int)
static constexpr size_t U_COEF   = 600320;     // 200000 (float)
static constexpr size_t U_DINV   = 800320;     // 100000 (float)
static constexpr size_t U_RANK_E = 900320;     // 1600000 (int)
static constexpr size_t U_RANK_N = 2500320;    // 1600000 (int)
static constexpr size_t U_CSR_EN = 4100320;    // 1600000 (int)  edge -> node ids
static constexpr size_t U_CSR_NE = 5700320;    // 1600000 (int)  node -> edge ids
static constexpr size_t U_R2     = 7300320;    // 6400000 (float) h1 / g1 / t2
static constexpr size_t U_R1     = 13700320;   // 12800000 (float) e1 / s2
// total = 26500320 * 4 B = 106 MB

// ---------------- CSR build ----------------

// histogram + per-incidence rank (rank writes are coalesced)
__global__ void k_hist_rank(const int* __restrict__ nidx, const int* __restrict__ eidx,
                            int* __restrict__ hist_n, int* __restrict__ hist_e,
                            int* __restrict__ rank_n, int* __restrict__ rank_e) {
    int i = blockIdx.x * blockDim.x + threadIdx.x;
    int stride = gridDim.x * blockDim.x;
    for (; i < N_INC_C; i += stride) {
        rank_e[i] = atomicAdd(&hist_e[eidx[i]], 1);
        rank_n[i] = atomicAdd(&hist_n[nidx[i]], 1);
    }
}

#define SCAN_ITEMS 8
#define SCAN_CHUNK 2048  // 256 threads * 8

__global__ __launch_bounds__(256) void k_scan_block_sums(const int* __restrict__ in,
                                                         int* __restrict__ bsum, int n) {
    __shared__ int lds[4];
    int base = blockIdx.x * SCAN_CHUNK + threadIdx.x * SCAN_ITEMS;
    int s = 0;
#pragma unroll
    for (int j = 0; j < SCAN_ITEMS; ++j) {
        int idx = base + j;
        s += (idx < n) ? in[idx] : 0;
    }
    for (int d = 1; d < 64; d <<= 1) s += __shfl_xor(s, d);
    if ((threadIdx.x & 63) == 0) lds[threadIdx.x >> 6] = s;
    __syncthreads();
    if (threadIdx.x == 0) bsum[blockIdx.x] = lds[0] + lds[1] + lds[2] + lds[3];
}

// single block of 64 threads, exclusive-scans bsum[0..nb), nb <= 128
__global__ void k_scan_bsum(int* bsum, int nb) {
    int t = threadIdx.x;
    int v0 = (2 * t < nb) ? bsum[2 * t] : 0;
    int v1 = (2 * t + 1 < nb) ? bsum[2 * t + 1] : 0;
    int s = v0 + v1;
    int incl = s;
    for (int d = 1; d < 64; d <<= 1) {
        int u = __shfl_up(incl, d);
        if (t >= d) incl += u;
    }
    int excl = incl - s;
    if (2 * t < nb) bsum[2 * t] = excl;
    if (2 * t + 1 < nb) bsum[2 * t + 1] = excl + v0;
}

__global__ __launch_bounds__(256) void k_scan_write(const int* __restrict__ in,
                                                    const int* __restrict__ bsum,
                                                    int* __restrict__ rowptr, int n, int total) {
    __shared__ int wsum[4];
    int tid = threadIdx.x;
    int base = blockIdx.x * SCAN_CHUNK + tid * SCAN_ITEMS;
    int v[SCAN_ITEMS];
    int s = 0;
#pragma unroll
    for (int j = 0; j < SCAN_ITEMS; ++j) {
        int idx = base + j;
        v[j] = (idx < n) ? in[idx] : 0;
        s += v[j];
    }
    int incl = s;
    int lane = tid & 63;
    for (int d = 1; d < 64; d <<= 1) {
        int u = __shfl_up(incl, d);
        if (lane >= d) incl += u;
    }
    if (lane == 63) wsum[tid >> 6] = incl;
    __syncthreads();
    int woff = 0;
    int w = tid >> 6;
    for (int i = 0; i < w; ++i) woff += wsum[i];
    int excl = woff + (incl - s) + bsum[blockIdx.x];
#pragma unroll
    for (int j = 0; j < SCAN_ITEMS; ++j) {
        int idx = base + j;
        if (idx < n) rowptr[idx] = excl;
        excl += v[j];
    }
    if (blockIdx.x == 0 && tid == 0) rowptr[n] = total;
}

// placement: one random-write stream per kernel, no atomics
__global__ void k_place_e(const int* __restrict__ nidx, const int* __restrict__ eidx,
                          const int* __restrict__ rank_e, const int* __restrict__ rpe,
                          int* __restrict__ csr_e_n) {
    int i = blockIdx.x * blockDim.x + threadIdx.x;
    int stride = gridDim.x * blockDim.x;
    for (; i < N_INC_C; i += stride)
        csr_e_n[rpe[eidx[i]] + rank_e[i]] = nidx[i];
}

__global__ void k_place_n(const int* __restrict__ nidx, const int* __restrict__ eidx,
                          const int* __restrict__ rank_n, const int* __restrict__ rpn,
                          int* __restrict__ csr_n_e) {
    int i = blockIdx.x * blockDim.x + threadIdx.x;
    int stride = gridDim.x * blockDim.x;
    for (; i < N_INC_C; i += stride)
        csr_n_e[rpn[nidx[i]] + rank_n[i]] = eidx[i];
}

__global__ void k_coef(const float* __restrict__ w, const int* __restrict__ rpe,
                       float* __restrict__ coef) {
    int i = blockIdx.x * blockDim.x + threadIdx.x;
    if (i >= N_EDGES_C) return;
    int bd = rpe[i + 1] - rpe[i];
    coef[i] = (bd > 0) ? w[i] / (float)bd : 0.0f;
}

__global__ void k_dinv(const int* __restrict__ rpn, const int* __restrict__ csr_n_e,
                       const float* __restrict__ w, float* __restrict__ Dinv) {
    int i = blockIdx.x * blockDim.x + threadIdx.x;
    if (i >= N_NODES_C) return;
    int s0 = rpn[i], s1 = rpn[i + 1];
    float s = 0.0f;
    for (int k = s0; k < s1; ++k) s += w[csr_n_e[k]];
    Dinv[i] = (s > 0.0f) ? 1.0f / s : 0.0f;
}

// ---------------- register-tiled dense GEMM ----------------
// Y[nrows x N] = X[nrows x K] @ W[K x N] (+bias, relu if EPI)
// 256 threads = 16 col-groups (tx) x 16 row-groups (ty); thread tile TM x TN.
template <int K, int N, int BM, int TM, int TN, int EPI>
__global__ __launch_bounds__(256) void k_gemm_rt(const float* __restrict__ X,
                                                 const float* __restrict__ W,
                                                 const float* __restrict__ bias,
                                                 float* __restrict__ Y, int nrows) {
    static_assert(16 * TN == N && 16 * TM == BM, "tile mismatch");
    __shared__ float Ws[K * N];
    __shared__ float Xs[BM][K + 4];   // +4: rows stay 16B-aligned, banks staggered

    int tid = threadIdx.x;
    int row0 = blockIdx.x * BM;

    // stage W (whole K x N) via float4
    for (int t = tid * 4; t < K * N; t += 1024)
        *reinterpret_cast<float4*>(&Ws[t]) = *reinterpret_cast<const float4*>(&W[t]);
    // stage X tile via float4
    for (int t = tid * 4; t < BM * K; t += 1024) {
        int r = t / K, k = t % K;
        int gr = row0 + r;
        float4 v;
        if (gr < nrows) v = *reinterpret_cast<const float4*>(&X[(size_t)gr * K + k]);
        else { v.x = v.y = v.z = v.w = 0.0f; }
        *reinterpret_cast<float4*>(&Xs[r][k]) = v;
    }
    __syncthreads();

    int tx = tid & 15;
    int ty = tid >> 4;
    float acc[TM][TN] = {};
#pragma unroll 8
    for (int k = 0; k < K; ++k) {
        float a[TM], b[TN];
#pragma unroll
        for (int m = 0; m < TM; ++m) a[m] = Xs[ty * TM + m][k];
#pragma unroll
        for (int n = 0; n < TN; ++n) b[n] = Ws[k * N + tx * TN + n];
#pragma unroll
        for (int m = 0; m < TM; ++m)
#pragma unroll
            for (int n = 0; n < TN; ++n) acc[m][n] += a[m] * b[n];
    }

#pragma unroll
    for (int m = 0; m < TM; ++m) {
        int gr = row0 + ty * TM + m;
        if (gr >= nrows) continue;
#pragma unroll
        for (int ng = 0; ng < TN / 4; ++ng) {
            float4 o;
            o.x = acc[m][ng * 4 + 0]; o.y = acc[m][ng * 4 + 1];
            o.z = acc[m][ng * 4 + 2]; o.w = acc[m][ng * 4 + 3];
            if (EPI) {
                const float4 b4 = *reinterpret_cast<const float4*>(&bias[tx * TN + ng * 4]);
                o.x += b4.x; o.y += b4.y; o.z += b4.z; o.w += b4.w;
                o.x = o.x > 0.0f ? o.x : 0.0f;
                o.y = o.y > 0.0f ? o.y : 0.0f;
                o.z = o.z > 0.0f ? o.z : 0.0f;
                o.w = o.w > 0.0f ? o.w : 0.0f;
            }
            *reinterpret_cast<float4*>(&Y[(size_t)gr * N + tx * TN + ng * 4]) = o;
        }
    }
}

// ---------------- CSR gathers: 4 neighbor-groups x 16 lanes x float4 ----------------
// EN=0: dst[r] = sum_{c in row} src[c]            (node -> edge)
// EN=1: dst[r] = Dinv[r] * sum coef[c]*src[c]     (edge -> node), FIN: +bias, relu
template <int EN, int FIN>
__global__ __launch_bounds__(256) void k_gather_v4(const int* __restrict__ rowptr,
                                                   const int* __restrict__ cols,
                                                   const float* __restrict__ coef,
                                                   const float* __restrict__ src,
                                                   const float* __restrict__ Dinv,
                                                   const float* __restrict__ bias,
                                                   float* __restrict__ dst, int nrows) {
    int wid = (blockIdx.x * 256 + threadIdx.x) >> 6;
    int lane = threadIdx.x & 63;
    int g = lane >> 4;        // neighbor group 0..3
    int gl = lane & 15;       // lane within group -> channels [gl*4, gl*4+4)
    int nw = (gridDim.x * 256) >> 6;
    for (int r = wid; r < nrows; r += nw) {
        int s0 = rowptr[r], s1 = rowptr[r + 1];
        float ax = 0.0f, ay = 0.0f, az = 0.0f, aw = 0.0f;
        for (int j = s0 + g; j < s1; j += 4) {
            int c = cols[j];  // uniform within group
            float s = EN ? coef[c] : 1.0f;
            const float4 v = *reinterpret_cast<const float4*>(&src[(size_t)c * 64 + gl * 4]);
            ax += s * v.x; ay += s * v.y; az += s * v.z; aw += s * v.w;
        }
        // reduce the 4 neighbor groups
        ax += __shfl_xor(ax, 16); ay += __shfl_xor(ay, 16);
        az += __shfl_xor(az, 16); aw += __shfl_xor(aw, 16);
        ax += __shfl_xor(ax, 32); ay += __shfl_xor(ay, 32);
        az += __shfl_xor(az, 32); aw += __shfl_xor(aw, 32);
        if (g == 0) {
            float4 o;
            o.x = ax; o.y = ay; o.z = az; o.w = aw;
            if (EN) {
                float dv = Dinv[r];
                o.x *= dv; o.y *= dv; o.z *= dv; o.w *= dv;
            }
            if (FIN) {
                const float4 b4 = *reinterpret_cast<const float4*>(&bias[gl * 4]);
                o.x += b4.x; o.y += b4.y; o.z += b4.z; o.w += b4.w;
                o.x = o.x > 0.0f ? o.x : 0.0f;
                o.y = o.y > 0.0f ? o.y : 0.0f;
                o.z = o.z > 0.0f ? o.z : 0.0f;
                o.w = o.w > 0.0f ? o.w : 0.0f;
            }
            *reinterpret_cast<float4*>(&dst[(size_t)r * 64 + gl * 4]) = o;
        }
    }
}

// ---------------- host ----------------

extern "C" void kernel_launch(void* const* d_in, const int* in_sizes, int n_in,
                              void* d_out, int out_size, void* d_ws, size_t ws_size,
                              hipStream_t stream) {
    const float* x   = (const float*)d_in[0];
    const int*   eix = (const int*)d_in[1];
    const float* w   = (const float*)d_in[2];
    const float* W1  = (const float*)d_in[4];
    const float* b1  = (const float*)d_in[5];
    const float* W2  = (const float*)d_in[6];
    const float* b2  = (const float*)d_in[7];
    float* out = (float*)d_out;

    const int* nidx = eix;
    const int* eidx = eix + N_INC_C;

    int*   wsI = (int*)d_ws;
    float* wsF = (float*)d_ws;
    int* hist_e = wsI + U_HIST_E;
    int* hist_n = wsI + U_HIST_N;
    int* rpe    = wsI + U_RPE;
    int* rpn    = wsI + U_RPN;
    int* bsum   = wsI + U_BSUM;
    float* coef = wsF + U_COEF;
    float* Dinv = wsF + U_DINV;
    int* rank_e = wsI + U_RANK_E;
    int* rank_n = wsI + U_RANK_N;
    int* csr_e_n = wsI + U_CSR_EN;
    int* csr_n_e = wsI + U_CSR_NE;
    float* h1 = wsF + U_R2;   // [N_NODES x 64]
    float* g1 = wsF + U_R2;   // reuses h1 (h1 dead when g1 written)
    float* t2 = wsF + U_R2;   // reuses g1 (g1 dead when t2 written)
    float* e1 = wsF + U_R1;   // [N_EDGES x 64]
    float* s2 = wsF + U_R1;   // reuses e1

    // ---- CSR build ----
    hipMemsetAsync(wsI, 0, 300000 * sizeof(int), stream);  // hist_e + hist_n
    k_hist_rank<<<2048, 256, 0, stream>>>(nidx, eidx, hist_n, hist_e, rank_n, rank_e);

    int nb_e = (N_EDGES_C + SCAN_CHUNK - 1) / SCAN_CHUNK;   // 98
    int nb_n = (N_NODES_C + SCAN_CHUNK - 1) / SCAN_CHUNK;   // 49
    k_scan_block_sums<<<nb_e, 256, 0, stream>>>(hist_e, bsum, N_EDGES_C);
    k_scan_bsum<<<1, 64, 0, stream>>>(bsum, nb_e);
    k_scan_write<<<nb_e, 256, 0, stream>>>(hist_e, bsum, rpe, N_EDGES_C, N_INC_C);
    k_scan_block_sums<<<nb_n, 256, 0, stream>>>(hist_n, bsum, N_NODES_C);
    k_scan_bsum<<<1, 64, 0, stream>>>(bsum, nb_n);
    k_scan_write<<<nb_n, 256, 0, stream>>>(hist_n, bsum, rpn, N_NODES_C, N_INC_C);

    k_place_e<<<2048, 256, 0, stream>>>(nidx, eidx, rank_e, rpe, csr_e_n);
    k_place_n<<<2048, 256, 0, stream>>>(nidx, eidx, rank_n, rpn, csr_n_e);
    k_coef<<<(N_EDGES_C + 255) / 256, 256, 0, stream>>>(w, rpe, coef);
    k_dinv<<<(N_NODES_C + 255) / 256, 256, 0, stream>>>(rpn, csr_n_e, w, Dinv);

    // ---- layer 1 ----
    k_gemm_rt<F_IN_C, H1_C, 32, 2, 4, 0><<<(N_NODES_C + 31) / 32, 256, 0, stream>>>(
        x, W1, nullptr, h1, N_NODES_C);
    k_gather_v4<0, 0><<<(N_EDGES_C + 3) / 4, 256, 0, stream>>>(rpe, csr_e_n, nullptr, h1,
                                                               nullptr, nullptr, e1, N_EDGES_C);
    k_gather_v4<1, 1><<<(N_NODES_C + 3) / 4, 256, 0, stream>>>(rpn, csr_n_e, coef, e1,
                                                               Dinv, b1, g1, N_NODES_C);

    // ---- layer 2 (aggregate in 64-dim, project 64->128 last) ----
    k_gather_v4<0, 0><<<(N_EDGES_C + 3) / 4, 256, 0, stream>>>(rpe, csr_e_n, nullptr, g1,
                                                               nullptr, nullptr, s2, N_EDGES_C);
    k_gather_v4<1, 0><<<(N_NODES_C + 3) / 4, 256, 0, stream>>>(rpn, csr_n_e, coef, s2,
                                                               Dinv, nullptr, t2, N_NODES_C);
    k_gemm_rt<H1_C, H2_C, 64, 4, 8, 1><<<(N_NODES_C + 63) / 64, 256, 0, stream>>>(
        t2, W2, b2, out, N_NODES_C);
}